// Round 4
// baseline (759.954 us; speedup 1.0000x reference)
//
#include <hip/hip_runtime.h>

#define B 8
#define N 100000
#define NE 3200000
#define CHUNK_LOG 10
#define CHUNK 1024            // nodes per chunk (LDS acc = 8*1032*4 = 33 KB)
#define CSTRIDE 1032          // padded batch stride: spreads phase2 atomics across banks
#define NCHUNK 98             // ceil(N / CHUNK)
#define NPAD 128              // scan width (pow2 >= NCHUNK)
#define CAP 70000             // per-bucket capacity (expect 65.3k +- 0.3k)
#define SEG 8                 // phase-2 blocks per chunk
#define EPB 512               // phase-1 edges per block (NE/EPB = 6250 exact)
#define RPB (2 * EPB)         // records staged per block = 1024
#define RSTRIDE 9             // LDS record stride in dwords (36 B, 9 coprime 32)

typedef float f32x4 __attribute__((ext_vector_type(4)));

// Static device scratch (graph-capture safe; recomputed fully every call).
// Fat SoA records: me + 8 signed flow values. Written COALESCED (bucket-grouped
// LDS staging + contiguous flush); read as a pure stream in phase2.
__device__ int   g_rec_me[(size_t)NCHUNK * CAP];                 // 27.4 MB
__device__ float g_rec_f[(size_t)NCHUNK * CAP * 8];              // 219.5 MB
__device__ int   g_cursor[NCHUNK];
__device__ float g_heads_t[N * B];                               // node-major heads
__device__ float g_partial[(size_t)NCHUNK * SEG * CHUNK * B];    // 25.7 MB
__device__ float g_accum;

// ---------------------------------------------------------------------------
__global__ __launch_bounds__(128) void zero_kernel() {
    int i = threadIdx.x;
    if (i < NCHUNK) g_cursor[i] = 0;
    if (i == 0) g_accum = 0.0f;
}

// heads (B,N) -> heads_t (N,B): each node's 8 batch values contiguous (32 B).
__global__ __launch_bounds__(256) void transpose_kernel(
    const float* __restrict__ node_heads)
{
    int i = blockIdx.x * blockDim.x + threadIdx.x;   // i = n*8 + b
    if (i >= N * B) return;
    int n = i >> 3, b = i & 7;
    g_heads_t[i] = node_heads[b * N + n];            // keep cached: phase1 gathers it
}

// ---------------------------------------------------------------------------
// Phase 1: flows + fat records, with ZERO scattered global stores.
// Records are slotted into bucket-grouped LDS (scatter absorbed by LDS),
// then flushed as contiguous coalesced NT runs into globally reserved ranges.
// ---------------------------------------------------------------------------
__global__ __launch_bounds__(256) void phase1_kernel(
    const int* __restrict__ edge_index,     // (2, E) int32
    const float* __restrict__ edge_attr,    // (E, 2)
    float* __restrict__ flows_out)          // (B, E)
{
    __shared__ int   s_s[EPB];
    __shared__ int   s_d[EPB];
    __shared__ int   hist[NCHUNK];      // block-local bucket counts
    __shared__ int   lbase[NCHUNK];     // exclusive prefix (LDS slot base)
    __shared__ int   gbase[NCHUNK];     // globally reserved base
    __shared__ int   lcur[NCHUNK];      // running staging cursor
    __shared__ int   scanbuf[NPAD];
    __shared__ float s_f[RPB * RSTRIDE];   // 36 KB, stride-9 spreads banks
    __shared__ int   s_me[RPB];

    int tid = threadIdx.x;
    int e0 = blockIdx.x * EPB;

    for (int i = tid; i < NCHUNK; i += 256) hist[i] = 0;
    __syncthreads();

    // pass A: histogram endpoint buckets; stage indices in LDS
    for (int i = tid; i < EPB; i += 256) {
        int e = e0 + i;
        int s = 0, d = 0;
        if (e < NE) {
            s = __builtin_nontemporal_load(&edge_index[e]);
            d = __builtin_nontemporal_load(&edge_index[NE + e]);
            atomicAdd(&hist[s >> CHUNK_LOG], 1);
            atomicAdd(&hist[d >> CHUNK_LOG], 1);
        }
        s_s[i] = s;
        s_d[i] = d;
    }
    __syncthreads();

    // Hillis-Steele inclusive scan over NPAD (syncs are non-divergent)
    if (tid < NPAD) scanbuf[tid] = (tid < NCHUNK) ? hist[tid] : 0;
    __syncthreads();
    for (int off = 1; off < NPAD; off <<= 1) {
        int v = 0;
        if (tid < NPAD && tid >= off) v = scanbuf[tid - off];
        __syncthreads();
        if (tid < NPAD && tid >= off) scanbuf[tid] += v;
        __syncthreads();
    }
    if (tid < NCHUNK) {
        int lb = scanbuf[tid] - hist[tid];
        lbase[tid] = lb;
        lcur[tid]  = lb;
        gbase[tid] = atomicAdd(&g_cursor[tid], hist[tid]);
    }
    __syncthreads();

    // pass B: 2-edge ILP — gathers for both edges in flight before stores
    {
        int idx0 = tid, idx1 = tid + 256;
        int ea = e0 + idx0, eb = e0 + idx1;
        bool va = ea < NE, vb = eb < NE;
        int s0 = s_s[idx0], d0 = s_d[idx0];
        int s1 = s_s[idx1], d1 = s_d[idx1];

        float c0 = va ? edge_attr[2 * (size_t)ea] : 0.0f;
        float c1 = vb ? edge_attr[2 * (size_t)eb] : 0.0f;

        const f32x4* hs0 = (const f32x4*)&g_heads_t[s0 << 3];
        const f32x4* hd0 = (const f32x4*)&g_heads_t[d0 << 3];
        const f32x4* hs1 = (const f32x4*)&g_heads_t[s1 << 3];
        const f32x4* hd1 = (const f32x4*)&g_heads_t[d1 << 3];
        f32x4 a00 = hs0[0], a01 = hs0[1];
        f32x4 b00 = hd0[0], b01 = hd0[1];
        f32x4 a10 = hs1[0], a11 = hs1[1];
        f32x4 b10 = hd1[0], b11 = hd1[1];

        f32x4 fa0 = c0 * (a00 - b00);
        f32x4 fa1 = c0 * (a01 - b01);
        f32x4 fb0 = c1 * (a10 - b10);
        f32x4 fb1 = c1 * (a11 - b11);

        if (va) {
            __builtin_nontemporal_store(fa0.x, &flows_out[0 * NE + ea]);
            __builtin_nontemporal_store(fa0.y, &flows_out[1 * NE + ea]);
            __builtin_nontemporal_store(fa0.z, &flows_out[2 * NE + ea]);
            __builtin_nontemporal_store(fa0.w, &flows_out[3 * NE + ea]);
            __builtin_nontemporal_store(fa1.x, &flows_out[4 * NE + ea]);
            __builtin_nontemporal_store(fa1.y, &flows_out[5 * NE + ea]);
            __builtin_nontemporal_store(fa1.z, &flows_out[6 * NE + ea]);
            __builtin_nontemporal_store(fa1.w, &flows_out[7 * NE + ea]);
        }
        if (vb) {
            __builtin_nontemporal_store(fb0.x, &flows_out[0 * NE + eb]);
            __builtin_nontemporal_store(fb0.y, &flows_out[1 * NE + eb]);
            __builtin_nontemporal_store(fb0.z, &flows_out[2 * NE + eb]);
            __builtin_nontemporal_store(fb0.w, &flows_out[3 * NE + eb]);
            __builtin_nontemporal_store(fb1.x, &flows_out[4 * NE + eb]);
            __builtin_nontemporal_store(fb1.y, &flows_out[5 * NE + eb]);
            __builtin_nontemporal_store(fb1.z, &flows_out[6 * NE + eb]);
            __builtin_nontemporal_store(fb1.w, &flows_out[7 * NE + eb]);
        }

        // stage 4 records into bucket-grouped LDS slots
        if (va) {
            int k0 = s0 >> CHUNK_LOG;
            int sl0 = atomicAdd(&lcur[k0], 1);
            s_me[sl0] = s0;
            float* p = &s_f[sl0 * RSTRIDE];
            p[0]=fa0.x; p[1]=fa0.y; p[2]=fa0.z; p[3]=fa0.w;
            p[4]=fa1.x; p[5]=fa1.y; p[6]=fa1.z; p[7]=fa1.w;
            int k1 = d0 >> CHUNK_LOG;
            int sl1 = atomicAdd(&lcur[k1], 1);
            s_me[sl1] = d0;
            float* q = &s_f[sl1 * RSTRIDE];
            q[0]=-fa0.x; q[1]=-fa0.y; q[2]=-fa0.z; q[3]=-fa0.w;
            q[4]=-fa1.x; q[5]=-fa1.y; q[6]=-fa1.z; q[7]=-fa1.w;
        }
        if (vb) {
            int k0 = s1 >> CHUNK_LOG;
            int sl0 = atomicAdd(&lcur[k0], 1);
            s_me[sl0] = s1;
            float* p = &s_f[sl0 * RSTRIDE];
            p[0]=fb0.x; p[1]=fb0.y; p[2]=fb0.z; p[3]=fb0.w;
            p[4]=fb1.x; p[5]=fb1.y; p[6]=fb1.z; p[7]=fb1.w;
            int k1 = d1 >> CHUNK_LOG;
            int sl1 = atomicAdd(&lcur[k1], 1);
            s_me[sl1] = d1;
            float* q = &s_f[sl1 * RSTRIDE];
            q[0]=-fb0.x; q[1]=-fb0.y; q[2]=-fb0.z; q[3]=-fb0.w;
            q[4]=-fb1.x; q[5]=-fb1.y; q[6]=-fb1.z; q[7]=-fb1.w;
        }
    }
    __syncthreads();

    // flush: wave w handles buckets w, w+4, ... — contiguous coalesced NT runs
    int wave = tid >> 6, lane = tid & 63;
    for (int k = wave; k < NCHUNK; k += 4) {
        int cnt = hist[k];
        if (cnt == 0) continue;
        int lb = lbase[k], gb = gbase[k];
        size_t fdst = ((size_t)k * CAP + gb) * 8;
        for (int i = lane; i < cnt * 8; i += 64) {
            int rec = i >> 3, j = i & 7;
            if (gb + rec < CAP)
                __builtin_nontemporal_store(s_f[(lb + rec) * RSTRIDE + j],
                                            &g_rec_f[fdst + (size_t)rec * 8 + j]);
        }
        size_t mdst = (size_t)k * CAP + gb;
        for (int i = lane; i < cnt; i += 64) {
            if (gb + i < CAP)
                __builtin_nontemporal_store(s_me[lb + i], &g_rec_me[mdst + i]);
        }
    }
}

// ---------------------------------------------------------------------------
// Phase 2: pure streaming — coalesced record reads, LDS accumulate, no gathers.
// ROUND-4 CHANGE: unsafeAtomicAdd -> native ds_add_f32 (fire-and-forget).
// Plain atomicAdd on __shared__ float lowers to a CAS retry-loop under hipcc's
// default IEEE-denormal mode (~2 dependent LDS round-trips per lane-op); that
// is the 341-us invariant wall of rounds 0/1/3.
// ---------------------------------------------------------------------------
#define ACC8(ME, F0, F1) do {                                          \
    int _ml = (ME) & (CHUNK - 1);                                      \
    unsafeAtomicAdd(&acc[0 * CSTRIDE + _ml], (F0).x);                  \
    unsafeAtomicAdd(&acc[1 * CSTRIDE + _ml], (F0).y);                  \
    unsafeAtomicAdd(&acc[2 * CSTRIDE + _ml], (F0).z);                  \
    unsafeAtomicAdd(&acc[3 * CSTRIDE + _ml], (F0).w);                  \
    unsafeAtomicAdd(&acc[4 * CSTRIDE + _ml], (F1).x);                  \
    unsafeAtomicAdd(&acc[5 * CSTRIDE + _ml], (F1).y);                  \
    unsafeAtomicAdd(&acc[6 * CSTRIDE + _ml], (F1).z);                  \
    unsafeAtomicAdd(&acc[7 * CSTRIDE + _ml], (F1).w);                  \
} while (0)

__global__ __launch_bounds__(256) void phase2_kernel() {
    __shared__ float acc[B * CSTRIDE];    // 33,024 B -> 4 blocks/CU resident
    int chunk = blockIdx.x / SEG;
    int seg   = blockIdx.x % SEG;

    for (int i = threadIdx.x; i < B * CSTRIDE; i += 256) acc[i] = 0.0f;
    __syncthreads();

    int cnt = g_cursor[chunk];
    if (cnt > CAP) cnt = CAP;
    size_t rbase = (size_t)chunk * CAP;

    const int STR = SEG * 256;
    int r = seg * 256 + threadIdx.x;
    for (; r + STR < cnt; r += 2 * STR) {
        size_t p0 = rbase + r;
        size_t p1 = rbase + r + STR;
        int me0 = __builtin_nontemporal_load(&g_rec_me[p0]);
        int me1 = __builtin_nontemporal_load(&g_rec_me[p1]);
        f32x4 f00 = __builtin_nontemporal_load((const f32x4*)&g_rec_f[p0 * 8]);
        f32x4 f01 = __builtin_nontemporal_load((const f32x4*)&g_rec_f[p0 * 8 + 4]);
        f32x4 f10 = __builtin_nontemporal_load((const f32x4*)&g_rec_f[p1 * 8]);
        f32x4 f11 = __builtin_nontemporal_load((const f32x4*)&g_rec_f[p1 * 8 + 4]);
        ACC8(me0, f00, f01);
        ACC8(me1, f10, f11);
    }
    if (r < cnt) {
        size_t p0 = rbase + r;
        int me0 = __builtin_nontemporal_load(&g_rec_me[p0]);
        f32x4 f00 = __builtin_nontemporal_load((const f32x4*)&g_rec_f[p0 * 8]);
        f32x4 f01 = __builtin_nontemporal_load((const f32x4*)&g_rec_f[p0 * 8 + 4]);
        ACC8(me0, f00, f01);
    }
    __syncthreads();

    // partial layout per block: [b][nl] (un-padded)
    float* out = &g_partial[(size_t)blockIdx.x * (CHUNK * B)];
    for (int i = threadIdx.x; i < CHUNK * B; i += 256) {
        int b  = i >> CHUNK_LOG;
        int nl = i & (CHUNK - 1);
        __builtin_nontemporal_store(acc[b * CSTRIDE + nl], &out[i]);
    }
}

// ---------------------------------------------------------------------------
// Merge partials + fused continuity reduction.
// ---------------------------------------------------------------------------
__global__ __launch_bounds__(256) void merge_cont_kernel(
    const float* __restrict__ demands)
{
    __shared__ float ssum[4];
    float local = 0.0f;
    int stride = gridDim.x * blockDim.x;
    for (int idx = blockIdx.x * blockDim.x + threadIdx.x; idx < N * B; idx += stride) {
        int b = idx / N;
        int n = idx - b * N;
        int chunk = n >> CHUNK_LOG;
        int nl = n & (CHUNK - 1);
        size_t base = ((size_t)(chunk * SEG) * B + b) * CHUNK + nl;
        float v = 0.0f;
#pragma unroll
        for (int s = 0; s < SEG; ++s)
            v += __builtin_nontemporal_load(&g_partial[base + (size_t)s * (B * CHUNK)]);
        v -= demands[idx];
        local = fmaf(v, v, local);
    }
    for (int off = 32; off > 0; off >>= 1)
        local += __shfl_down(local, off, 64);
    int lane = threadIdx.x & 63, wave = threadIdx.x >> 6;
    if (lane == 0) ssum[wave] = local;
    __syncthreads();
    if (threadIdx.x == 0)
        unsafeAtomicAdd(&g_accum, ssum[0] + ssum[1] + ssum[2] + ssum[3]);
}

// ---------------------------------------------------------------------------
// Boundary loss + finalize scalars.
// ---------------------------------------------------------------------------
__global__ __launch_bounds__(512) void finalize_kernel(
    const float* __restrict__ node_heads,
    const int* __restrict__ res_nodes,      // (64,) int32
    const float* __restrict__ res_head,     // (1,)
    float* __restrict__ out)
{
    __shared__ float ssum[8];
    int t = threadIdx.x;          // 512 = B*64
    int b = t >> 6;
    int j = t & 63;
    float pred = node_heads[b * N + res_nodes[j]];
    float diff = pred - res_head[0];
    float local = diff * diff;
    for (int off = 32; off > 0; off >>= 1)
        local += __shfl_down(local, off, 64);
    if ((t & 63) == 0) ssum[t >> 6] = local;
    __syncthreads();
    if (t == 0) {
        float bsum = 0.0f;
        for (int w = 0; w < 8; ++w) bsum += ssum[w];
        float boundary = bsum / 512.0f;
        float continuity = g_accum / (float)(B * N);
        out[0] = continuity;
        out[1] = boundary;
        out[2] = continuity + boundary;     // LAMBDA_PHYSICS = 1.0
    }
}

extern "C" void kernel_launch(void* const* d_in, const int* in_sizes, int n_in,
                              void* d_out, int out_size, void* d_ws, size_t ws_size,
                              hipStream_t stream) {
    const float* node_heads = (const float*)d_in[0];
    const float* demands    = (const float*)d_in[1];
    const int*   edge_index = (const int*)d_in[2];    // int32 per harness
    const float* edge_attr  = (const float*)d_in[3];
    const int*   res_nodes  = (const int*)d_in[4];    // int32 per harness
    const float* res_head   = (const float*)d_in[5];

    float* out = (float*)d_out;   // [cont, bound, total, flows(B,E)]

    zero_kernel<<<1, 128, 0, stream>>>();
    transpose_kernel<<<(N * B + 255) / 256, 256, 0, stream>>>(node_heads);
    phase1_kernel<<<(NE + EPB - 1) / EPB, 256, 0, stream>>>(
        edge_index, edge_attr, out + 3);
    phase2_kernel<<<NCHUNK * SEG, 256, 0, stream>>>();
    merge_cont_kernel<<<1024, 256, 0, stream>>>(demands);
    finalize_kernel<<<1, 512, 0, stream>>>(node_heads, res_nodes, res_head, out);
}

// Round 6
// 501.708 us; speedup vs baseline: 1.5147x; 1.5147x over previous
//
#include <hip/hip_runtime.h>

#define B 8
#define N 100000
#define NE 3200000
#define CHUNK2_LOG 7
#define CHUNK2 128            // nodes per record bucket
#define NCHUNK2 782           // ceil(N / 128)
#define CAP2 9216             // per-bucket record capacity (mean 8192, +11 sigma)
#define CAPH 4800             // per-64-node-half LDS capacity (mean 4096, +11 sigma)
#define EPB 2048              // phase-1 edges per block
#define RPB (2 * EPB)         // records staged per block
#define SCANW 1024            // phase-1 scan width (pow2 >= NCHUNK2)

typedef float f32x4 __attribute__((ext_vector_type(4)));
typedef unsigned u32x2 __attribute__((ext_vector_type(2)));   // NT-store-compatible

// Static device scratch (graph-capture safe; recomputed fully every call).
// Thin 8-B records: key = (me_local<<17)|other, val = conductance bits.
// Contribution to node me is ALWAYS +c*(h[me]-h[other]) for both endpoints,
// so no sign is stored. Written coalesced (LDS bucket staging), read as a
// stream, sorted per-node in LDS, accumulated in REGISTERS (zero fp atomics
// -> sidesteps the measured ~4 cy/lane LDS fp-atomic wall of rounds 0-4).
__device__ u32x2 g_rec2[(size_t)NCHUNK2 * CAP2];                 // 57.7 MB
__device__ int   g_cursor2[NCHUNK2];
__device__ float g_heads_t[N * B];                               // node-major heads
__device__ float g_accum;

// ---------------------------------------------------------------------------
__global__ __launch_bounds__(256) void zero_kernel() {
    for (int i = threadIdx.x; i < NCHUNK2; i += 256) g_cursor2[i] = 0;
    if (threadIdx.x == 0) g_accum = 0.0f;
}

// heads (B,N) -> heads_t (N,B): each node's 8 batch values contiguous (32 B).
__global__ __launch_bounds__(256) void transpose_kernel(
    const float* __restrict__ node_heads)
{
    int i = blockIdx.x * blockDim.x + threadIdx.x;   // i = n*8 + b
    if (i >= N * B) return;
    int n = i >> 3, b = i & 7;
    g_heads_t[i] = node_heads[b * N + n];            // stays L2-hot for gathers
}

// ---------------------------------------------------------------------------
// Phase 1: flows + thin records bucketed by 128-node chunk.
// LDS staging -> coalesced flush (round-3 pattern, proven); 153 MB written
// vs round-3's 332 MB (phase1 is NT-store-rate-bound at ~1 TB/s).
// ---------------------------------------------------------------------------
__global__ __launch_bounds__(256) void phase1_kernel(
    const int* __restrict__ edge_index,     // (2, E) int32
    const float* __restrict__ edge_attr,    // (E, 2)
    float* __restrict__ flows_out)          // (B, E)
{
    __shared__ int   hist[NCHUNK2];
    __shared__ int   lbase[NCHUNK2];
    __shared__ int   gbase[NCHUNK2];
    __shared__ int   lcur[NCHUNK2];
    __shared__ int   scanbuf[SCANW];
    __shared__ u32x2 s_rec[RPB];        // 32 KB staging

    int tid = threadIdx.x;
    int e0 = blockIdx.x * EPB;

    for (int i = tid; i < NCHUNK2; i += 256) hist[i] = 0;
    __syncthreads();

    // pass A: histogram endpoint buckets (plain loads -> warm L1/L2 for pass B)
    for (int i = tid; i < EPB; i += 256) {
        int e = e0 + i;
        if (e < NE) {
            int s = edge_index[e];
            int d = edge_index[NE + e];
            atomicAdd(&hist[s >> CHUNK2_LOG], 1);
            atomicAdd(&hist[d >> CHUNK2_LOG], 1);
        }
    }
    __syncthreads();

    // Hillis-Steele inclusive scan over SCANW (non-divergent syncs)
    for (int i = tid; i < SCANW; i += 256)
        scanbuf[i] = (i < NCHUNK2) ? hist[i] : 0;
    __syncthreads();
    for (int off = 1; off < SCANW; off <<= 1) {
        int v[SCANW / 256];
#pragma unroll
        for (int j = 0; j < SCANW / 256; ++j) {
            int i = tid + j * 256;
            v[j] = (i >= off) ? scanbuf[i - off] : 0;
        }
        __syncthreads();
#pragma unroll
        for (int j = 0; j < SCANW / 256; ++j) {
            int i = tid + j * 256;
            if (i >= off) scanbuf[i] += v[j];
        }
        __syncthreads();
    }
    for (int i = tid; i < NCHUNK2; i += 256) {
        int lb = scanbuf[i] - hist[i];
        lbase[i] = lb;
        lcur[i]  = lb;
        gbase[i] = atomicAdd(&g_cursor2[i], hist[i]);
    }
    __syncthreads();

    // pass B: flows + stage 2 records per edge into bucket-grouped LDS
    for (int i = tid; i < EPB; i += 256) {
        int e = e0 + i;
        if (e >= NE) continue;
        int s = edge_index[e];
        int d = edge_index[NE + e];
        float c = edge_attr[2 * (size_t)e];

        const f32x4* hs4 = (const f32x4*)&g_heads_t[s << 3];
        const f32x4* hd4 = (const f32x4*)&g_heads_t[d << 3];
        f32x4 a0 = hs4[0], a1 = hs4[1];
        f32x4 b0 = hd4[0], b1 = hd4[1];
        f32x4 f0 = c * (a0 - b0);
        f32x4 f1 = c * (a1 - b1);

        __builtin_nontemporal_store(f0.x, &flows_out[0 * NE + e]);
        __builtin_nontemporal_store(f0.y, &flows_out[1 * NE + e]);
        __builtin_nontemporal_store(f0.z, &flows_out[2 * NE + e]);
        __builtin_nontemporal_store(f0.w, &flows_out[3 * NE + e]);
        __builtin_nontemporal_store(f1.x, &flows_out[4 * NE + e]);
        __builtin_nontemporal_store(f1.y, &flows_out[5 * NE + e]);
        __builtin_nontemporal_store(f1.z, &flows_out[6 * NE + e]);
        __builtin_nontemporal_store(f1.w, &flows_out[7 * NE + e]);

        unsigned cb = __float_as_uint(c);
        int ks = s >> CHUNK2_LOG;
        int sl = atomicAdd(&lcur[ks], 1);
        u32x2 rs; rs.x = ((unsigned)(s & (CHUNK2 - 1)) << 17) | (unsigned)d; rs.y = cb;
        s_rec[sl] = rs;
        int kd = d >> CHUNK2_LOG;
        sl = atomicAdd(&lcur[kd], 1);
        u32x2 rd; rd.x = ((unsigned)(d & (CHUNK2 - 1)) << 17) | (unsigned)s; rd.y = cb;
        s_rec[sl] = rd;
    }
    __syncthreads();

    // flush: wave w handles buckets w, w+4, ... — contiguous NT runs
    int wave = tid >> 6, lane = tid & 63;
    for (int k = wave; k < NCHUNK2; k += 4) {
        int cnt = hist[k];
        if (cnt == 0) continue;
        int lb = lbase[k], gb = gbase[k];
        u32x2* dst = &g_rec2[(size_t)k * CAP2];
        for (int i = lane; i < cnt; i += 64) {
            if (gb + i < CAP2)
                __builtin_nontemporal_store(s_rec[lb + i], &dst[gb + i]);
        }
    }
}

// ---------------------------------------------------------------------------
// Sort-gather: per 128-node chunk (two 64-node halves in 39 KB LDS):
// counting-sort records by node into LDS runs (int atomics only), then each
// node's run is accumulated in REGISTERS by a 4-lane group (gathers of
// h[other] hit L2-resident g_heads_t). Violation^2 reduced in-block into
// g_accum. No fp atomics, no partials buffer, no merge kernel.
// ---------------------------------------------------------------------------
__global__ __launch_bounds__(256) void sortgather_kernel(
    const float* __restrict__ demands)
{
    __shared__ u32x2 s_rec[CAPH];       // 37.5 KB sorted (other, c) runs
    __shared__ int   hist[64];
    __shared__ int   hbase[64];
    __shared__ int   hcur[64];
    __shared__ int   scanbuf[64];
    __shared__ float wred[4];

    int tid = threadIdx.x;
    int c = blockIdx.x;
    int cnt = g_cursor2[c];
    if (cnt > CAP2) cnt = CAP2;
    const u32x2* rec = &g_rec2[(size_t)c * CAP2];

    float contrib = 0.0f;

    for (int h = 0; h < 2; ++h) {
        if (tid < 64) hist[tid] = 0;
        __syncthreads();

        // count this half's nodes
        for (int i = tid; i < cnt; i += 256) {
            int ml = (int)(rec[i].x >> 17);
            if ((ml >> 6) == h) atomicAdd(&hist[ml & 63], 1);
        }
        __syncthreads();

        // exclusive scan over 64 (non-divergent syncs)
        if (tid < 64) scanbuf[tid] = hist[tid];
        __syncthreads();
        for (int off = 1; off < 64; off <<= 1) {
            int v = (tid < 64 && tid >= off) ? scanbuf[tid - off] : 0;
            __syncthreads();
            if (tid < 64 && tid >= off) scanbuf[tid] += v;
            __syncthreads();
        }
        if (tid < 64) {
            int b0 = scanbuf[tid] - hist[tid];
            hbase[tid] = b0;
            hcur[tid]  = b0;
        }
        __syncthreads();

        // place records into per-node runs
        for (int i = tid; i < cnt; i += 256) {
            u32x2 r = rec[i];
            int ml = (int)(r.x >> 17);
            if ((ml >> 6) == h) {
                int sl = atomicAdd(&hcur[ml & 63], 1);
                if (sl < CAPH) {
                    u32x2 rr; rr.x = r.x & 0x1FFFFu; rr.y = r.y;
                    s_rec[sl] = rr;
                }
            }
        }
        __syncthreads();

        // owner accumulate: 4 lanes per node, registers only
        int nl = tid >> 2, p = tid & 3;
        int n = (c << CHUNK2_LOG) + (h << 6) + nl;
        int off0 = hbase[nl];
        int cn = hist[nl];
        if (off0 + cn > CAPH) cn = (CAPH > off0) ? (CAPH - off0) : 0;
        int nc = (n < N) ? n : 0;
        const f32x4* hm = (const f32x4*)&g_heads_t[nc << 3];
        f32x4 m0 = hm[0], m1 = hm[1];
        f32x4 a0 = {0.f, 0.f, 0.f, 0.f};
        f32x4 a1 = {0.f, 0.f, 0.f, 0.f};
        for (int i = p; i < cn; i += 4) {
            u32x2 r = s_rec[off0 + i];
            float cc = __uint_as_float(r.y);
            const f32x4* ho = (const f32x4*)&g_heads_t[r.x << 3];
            f32x4 o0 = ho[0], o1 = ho[1];
            a0 += cc * (m0 - o0);
            a1 += cc * (m1 - o1);
        }
        float acc[8] = {a0.x, a0.y, a0.z, a0.w, a1.x, a1.y, a1.z, a1.w};
        bool emit = (p == 0) && (n < N);
#pragma unroll
        for (int j = 0; j < 8; ++j) {
            float v = acc[j];
            v += __shfl_xor(v, 1, 64);
            v += __shfl_xor(v, 2, 64);
            if (emit) {
                float vv = v - demands[j * N + n];
                contrib = fmaf(vv, vv, contrib);
            }
        }
        __syncthreads();   // LDS reused next half
    }

    // block reduction of continuity partial
    for (int off = 32; off > 0; off >>= 1)
        contrib += __shfl_down(contrib, off, 64);
    int wave = tid >> 6, lane = tid & 63;
    if (lane == 0) wred[wave] = contrib;
    __syncthreads();
    if (tid == 0)
        unsafeAtomicAdd(&g_accum, wred[0] + wred[1] + wred[2] + wred[3]);
}

// ---------------------------------------------------------------------------
// Boundary loss + finalize scalars.
// ---------------------------------------------------------------------------
__global__ __launch_bounds__(512) void finalize_kernel(
    const float* __restrict__ node_heads,
    const int* __restrict__ res_nodes,      // (64,) int32
    const float* __restrict__ res_head,     // (1,)
    float* __restrict__ out)
{
    __shared__ float ssum[8];
    int t = threadIdx.x;          // 512 = B*64
    int b = t >> 6;
    int j = t & 63;
    float pred = node_heads[b * N + res_nodes[j]];
    float diff = pred - res_head[0];
    float local = diff * diff;
    for (int off = 32; off > 0; off >>= 1)
        local += __shfl_down(local, off, 64);
    if ((t & 63) == 0) ssum[t >> 6] = local;
    __syncthreads();
    if (t == 0) {
        float bsum = 0.0f;
        for (int w = 0; w < 8; ++w) bsum += ssum[w];
        float boundary = bsum / 512.0f;
        float continuity = g_accum / (float)(B * N);
        out[0] = continuity;
        out[1] = boundary;
        out[2] = continuity + boundary;     // LAMBDA_PHYSICS = 1.0
    }
}

extern "C" void kernel_launch(void* const* d_in, const int* in_sizes, int n_in,
                              void* d_out, int out_size, void* d_ws, size_t ws_size,
                              hipStream_t stream) {
    const float* node_heads = (const float*)d_in[0];
    const float* demands    = (const float*)d_in[1];
    const int*   edge_index = (const int*)d_in[2];    // int32 per harness
    const float* edge_attr  = (const float*)d_in[3];
    const int*   res_nodes  = (const int*)d_in[4];    // int32 per harness
    const float* res_head   = (const float*)d_in[5];

    float* out = (float*)d_out;   // [cont, bound, total, flows(B,E)]

    zero_kernel<<<1, 256, 0, stream>>>();
    transpose_kernel<<<(N * B + 255) / 256, 256, 0, stream>>>(node_heads);
    phase1_kernel<<<(NE + EPB - 1) / EPB, 256, 0, stream>>>(
        edge_index, edge_attr, out + 3);
    sortgather_kernel<<<NCHUNK2, 256, 0, stream>>>(demands);
    finalize_kernel<<<1, 512, 0, stream>>>(node_heads, res_nodes, res_head, out);
}